// Round 7
// baseline (174.171 us; speedup 1.0000x reference)
//
#include <hip/hip_runtime.h>
#include <math.h>

typedef _Float16 half8 __attribute__((ext_vector_type(8)));

#define NT  256
#define SPB 84          // samples/block, 3 threads/sample (rows n and n+3): 252 active

// ---- float-index offsets into Wsh (f32 view); weight tables are f16-packed ----
#define FH_REC   0      // 32 rows x 8 floats (16 f16/row): A[6],B[6],c0,w2,pad2
#define FH_WD1   256    // 6  x 16 (32 f16/row) [m][o]
#define FH_WD2   352    // 32 x 16 [k][o]
#define FH_WD3T  864    // 6  x 16 [j][k] (transposed)
#define FH_WS1   960    // 18 x 16 [m][o]
#define FH_WS2   1248   // 32 x 8  (16 f16/row) [k][o]
#define FH_WS3   1504   // 8  (16 f16)
#define FF_BD1   1512   // f32 region
#define FF_BD2   1544
#define FF_BD3   1576   // 6 + 2 pad
#define FF_BS1   1584
#define FF_BS2   1616
#define FF_MISC  1632   // [0]=bs3 [1]=be2
#define W_TOTF   1640   // 6560 bytes

#define ADJ_STRIDE 52

__device__ __forceinline__ float sigmoidf_(float x) {
    return 1.0f / (1.0f + __expf(-x));
}

// One block, 512 threads: fold edge weights, convert all tables to f16, pack into cat.
__global__ __launch_bounds__(512) void fold_kernel(
        const float* __restrict__ Wn,  const float* __restrict__ bn,
        const float* __restrict__ We1, const float* __restrict__ be1,
        const float* __restrict__ We2, const float* __restrict__ be2,
        const float* __restrict__ Wd1, const float* __restrict__ bd1,
        const float* __restrict__ Wd2, const float* __restrict__ bd2,
        const float* __restrict__ Wd3, const float* __restrict__ bd3,
        const float* __restrict__ Ws1, const float* __restrict__ bs1,
        const float* __restrict__ Ws2, const float* __restrict__ bs2,
        const float* __restrict__ Ws3, const float* __restrict__ bs3,
        float* __restrict__ cat) {
    _Float16* cath = (_Float16*)cat;
    const int t = threadIdx.x;
    // REC: 512 f16, one per thread
    {
        const int h = t >> 4, sl = t & 15;
        float val = 0.0f;
        if (sl < 6) {
            #pragma unroll
            for (int k = 0; k < 32; ++k) val = fmaf(Wn[sl*32+k], We1[k*32+h], val);
        } else if (sl < 12) {
            const int m = sl - 6;
            #pragma unroll
            for (int k = 0; k < 32; ++k) val = fmaf(Wn[m*32+k], We1[(32+k)*32+h], val);
        } else if (sl == 12) {
            #pragma unroll
            for (int k = 0; k < 32; ++k) val = fmaf(bn[k], We1[k*32+h] + We1[(32+k)*32+h], val);
            val += be1[h];
        } else if (sl == 13) {
            val = We2[h];
        }
        cath[h*16 + sl] = (_Float16)val;
    }
    // remaining f16 tables: half-index 512..3023
    for (int i = 512 + t; i < 3024; i += 512) {
        float v = 0.0f;
        if      (i < 704)  v = Wd1[i - 512];
        else if (i < 1728) v = Wd2[i - 704];
        else if (i < 1920) { const int q = i - 1728; v = Wd3[(q & 31)*6 + (q >> 5)]; }
        else if (i < 2496) v = Ws1[i - 1920];
        else if (i < 3008) v = Ws2[i - 2496];
        else               v = Ws3[i - 3008];
        cath[i] = (_Float16)v;
    }
    // f32 region: 128 floats at float-index 1512
    if (t < 128) {
        const int q = t;
        float v = 0.0f;
        if      (q < 32)  v = bd1[q];
        else if (q < 64)  v = bd2[q-32];
        else if (q < 70)  v = bd3[q-64];
        else if (q < 72)  v = 0.0f;
        else if (q < 104) v = bs1[q-72];
        else if (q < 120) v = bs2[q-104];
        else if (q == 120) v = bs3[0];
        else if (q == 121) v = be2[0];
        cat[1512 + q] = v;
    }
}

__global__ __launch_bounds__(NT, 1) void fused5_kernel(
        const float* __restrict__ factors, const float* __restrict__ cat,
        float* __restrict__ adj_out, float* __restrict__ pred_out,
        float* __restrict__ scores, int B) {
    __shared__ __align__(16) float Wsh[W_TOTF];
    __shared__ __align__(16) float adj_s[SPB * ADJ_STRIDE];
    __shared__ float sc_s[SPB * 6];

    const int t = threadIdx.x;
    // stage cat -> LDS (16B per thread per iter)
    #pragma unroll
    for (int i0 = 0; i0 < 2048; i0 += NT * 4) {
        const int i = i0 + t * 4;
        if (i < W_TOTF)
            *reinterpret_cast<float4*>(&Wsh[i]) = *reinterpret_cast<const float4*>(&cat[i]);
    }

    const int s = t / 3;
    const int n = t - s * 3;              // rows n and n+3
    const int b = blockIdx.x * SPB + s;
    const bool act = (t < SPB * 3);
    const int sl_ = (s < SPB) ? s : (SPB - 1);
    const bool bv = act && (b < B);

    float fall[36], fi0[6], fi1[6];
    #pragma unroll
    for (int q = 0; q < 36; ++q) fall[q] = 0.0f;
    #pragma unroll
    for (int m = 0; m < 6; ++m) { fi0[m] = 0.0f; fi1[m] = 0.0f; }
    if (bv) {
        const float* f = factors + (size_t)b * 36;
        #pragma unroll
        for (int q = 0; q < 9; ++q) {
            const float4 v = reinterpret_cast<const float4*>(f)[q];
            fall[q*4+0] = v.x; fall[q*4+1] = v.y; fall[q*4+2] = v.z; fall[q*4+3] = v.w;
        }
        #pragma unroll
        for (int m = 0; m < 6; ++m) { fi0[m] = fall[n*6 + m]; fi1[m] = fall[(n+3)*6 + m]; }
    }
    __syncthreads();

    // ================= edge phase (rows n, n+3; vj shared) =================
    float av0[6], av1[6];
    {
        float acc0[6] = {0.f,0.f,0.f,0.f,0.f,0.f};
        float acc1[6] = {0.f,0.f,0.f,0.f,0.f,0.f};
        #pragma unroll 4
        for (int h = 0; h < 32; ++h) {
            const half8 ha = *reinterpret_cast<const half8*>(&Wsh[FH_REC + h*8]);
            const half8 hb = *reinterpret_cast<const half8*>(&Wsh[FH_REC + h*8 + 4]);
            const float A0=(float)ha[0], A1=(float)ha[1], A2=(float)ha[2];
            const float A3=(float)ha[3], A4=(float)ha[4], A5=(float)ha[5];
            const float B0=(float)ha[6], B1=(float)ha[7], B2=(float)hb[0];
            const float B3=(float)hb[1], B4=(float)hb[2], B5=(float)hb[3];
            const float c0=(float)hb[4], w2=(float)hb[5];
            float uh0 = c0, uh1 = c0;
            uh0 = fmaf(fi0[0], A0, uh0); uh1 = fmaf(fi1[0], A0, uh1);
            uh0 = fmaf(fi0[1], A1, uh0); uh1 = fmaf(fi1[1], A1, uh1);
            uh0 = fmaf(fi0[2], A2, uh0); uh1 = fmaf(fi1[2], A2, uh1);
            uh0 = fmaf(fi0[3], A3, uh0); uh1 = fmaf(fi1[3], A3, uh1);
            uh0 = fmaf(fi0[4], A4, uh0); uh1 = fmaf(fi1[4], A4, uh1);
            uh0 = fmaf(fi0[5], A5, uh0); uh1 = fmaf(fi1[5], A5, uh1);
            #pragma unroll
            for (int j = 0; j < 6; ++j) {
                float vj = fall[j*6+0] * B0;
                vj = fmaf(fall[j*6+1], B1, vj);
                vj = fmaf(fall[j*6+2], B2, vj);
                vj = fmaf(fall[j*6+3], B3, vj);
                vj = fmaf(fall[j*6+4], B4, vj);
                vj = fmaf(fall[j*6+5], B5, vj);
                acc0[j] = fmaf(fmaxf(uh0 + vj, 0.0f), w2, acc0[j]);
                acc1[j] = fmaf(fmaxf(uh1 + vj, 0.0f), w2, acc1[j]);
            }
        }
        const float b2 = Wsh[FF_MISC + 1];
        #pragma unroll
        for (int j = 0; j < 6; ++j) {
            av0[j] = (j == n)     ? 0.0f : sigmoidf_(acc0[j] + b2);
            av1[j] = (j == n + 3) ? 0.0f : sigmoidf_(acc1[j] + b2);
        }
    }
    if (act) {
        float* as = &adj_s[sl_ * ADJ_STRIDE];
        *reinterpret_cast<float4*>(&as[n*8])       = make_float4(av0[0], av0[1], av0[2], av0[3]);
        *reinterpret_cast<float2*>(&as[n*8+4])     = make_float2(av0[4], av0[5]);
        *reinterpret_cast<float4*>(&as[(n+3)*8])   = make_float4(av1[0], av1[1], av1[2], av1[3]);
        *reinterpret_cast<float2*>(&as[(n+3)*8+4]) = make_float2(av1[4], av1[5]);
    }
    if (bv) {
        float* ao = adj_out + (size_t)b * 36 + n * 6;
        *reinterpret_cast<float2*>(&ao[0])  = make_float2(av0[0], av0[1]);
        *reinterpret_cast<float2*>(&ao[2])  = make_float2(av0[2], av0[3]);
        *reinterpret_cast<float2*>(&ao[4])  = make_float2(av0[4], av0[5]);
        *reinterpret_cast<float2*>(&ao[18]) = make_float2(av1[0], av1[1]);
        *reinterpret_cast<float2*>(&ao[20]) = make_float2(av1[2], av1[3]);
        *reinterpret_cast<float2*>(&ao[22]) = make_float2(av1[4], av1[5]);
    }
    __syncthreads();

    // ================= structured =================
    float st0[6], st1[6];
    {
        const float* as = &adj_s[sl_ * ADJ_STRIDE];
        #pragma unroll
        for (int i = 0; i < 6; ++i) {
            const float4 qa = *reinterpret_cast<const float4*>(&as[i*8]);
            const float2 qb = *reinterpret_cast<const float2*>(&as[i*8+4]);
            float v = fi0[0] * qa.x;
            v = fmaf(fi0[1], qa.y, v); v = fmaf(fi0[2], qa.z, v);
            v = fmaf(fi0[3], qa.w, v); v = fmaf(fi0[4], qb.x, v);
            v = fmaf(fi0[5], qb.y, v);
            st0[i] = v;
            float w = fi1[0] * qa.x;
            w = fmaf(fi1[1], qa.y, w); w = fmaf(fi1[2], qa.z, w);
            w = fmaf(fi1[3], qa.w, w); w = fmaf(fi1[4], qb.x, w);
            w = fmaf(fi1[5], qb.y, w);
            st1[i] = w;
        }
    }

    // ================= h1 = relu(st @ Wd1 + bd1) =================
    float h1a[32], h1b[32];
    #pragma unroll
    for (int o4 = 0; o4 < 8; ++o4) {
        const float4 v = *reinterpret_cast<const float4*>(&Wsh[FF_BD1 + o4*4]);
        h1a[o4*4+0] = v.x; h1a[o4*4+1] = v.y; h1a[o4*4+2] = v.z; h1a[o4*4+3] = v.w;
        h1b[o4*4+0] = v.x; h1b[o4*4+1] = v.y; h1b[o4*4+2] = v.z; h1b[o4*4+3] = v.w;
    }
    #pragma unroll
    for (int m = 0; m < 6; ++m) {
        const float xa = st0[m], xb = st1[m];
        #pragma unroll
        for (int q = 0; q < 4; ++q) {
            const half8 w = *reinterpret_cast<const half8*>(&Wsh[FH_WD1 + m*16 + q*4]);
            #pragma unroll
            for (int e = 0; e < 8; ++e) {
                const float wf = (float)w[e];
                h1a[q*8+e] = fmaf(xa, wf, h1a[q*8+e]);
                h1b[q*8+e] = fmaf(xb, wf, h1b[q*8+e]);
            }
        }
    }
    #pragma unroll
    for (int o = 0; o < 32; ++o) { h1a[o] = fmaxf(h1a[o], 0.0f); h1b[o] = fmaxf(h1b[o], 0.0f); }

    // ================= h2 = relu(h1 @ Wd2 + bd2), 2 passes of 16 outs =================
    float h2a[32], h2b[32];
    #pragma unroll
    for (int o4 = 0; o4 < 8; ++o4) {
        const float4 v = *reinterpret_cast<const float4*>(&Wsh[FF_BD2 + o4*4]);
        h2a[o4*4+0] = v.x; h2a[o4*4+1] = v.y; h2a[o4*4+2] = v.z; h2a[o4*4+3] = v.w;
        h2b[o4*4+0] = v.x; h2b[o4*4+1] = v.y; h2b[o4*4+2] = v.z; h2b[o4*4+3] = v.w;
    }
    #pragma unroll
    for (int p = 0; p < 2; ++p) {
        #pragma unroll
        for (int k = 0; k < 32; ++k) {
            const half8 w0 = *reinterpret_cast<const half8*>(&Wsh[FH_WD2 + k*16 + p*8]);
            const half8 w1 = *reinterpret_cast<const half8*>(&Wsh[FH_WD2 + k*16 + p*8 + 4]);
            const float xa = h1a[k], xb = h1b[k];
            #pragma unroll
            for (int e = 0; e < 8; ++e) {
                const float we0 = (float)w0[e], we1 = (float)w1[e];
                h2a[p*16+e]   = fmaf(xa, we0, h2a[p*16+e]);
                h2b[p*16+e]   = fmaf(xb, we0, h2b[p*16+e]);
                h2a[p*16+8+e] = fmaf(xa, we1, h2a[p*16+8+e]);
                h2b[p*16+8+e] = fmaf(xb, we1, h2b[p*16+8+e]);
            }
        }
    }
    #pragma unroll
    for (int o = 0; o < 32; ++o) { h2a[o] = fmaxf(h2a[o], 0.0f); h2b[o] = fmaxf(h2b[o], 0.0f); }

    // ================= pred = h2 @ Wd3 + bd3 (Wd3T [j][k]) =================
    float pra[6], prb[6];
    #pragma unroll
    for (int j = 0; j < 6; ++j) {
        float va = Wsh[FF_BD3 + j], vb = va;
        #pragma unroll
        for (int q = 0; q < 4; ++q) {
            const half8 w = *reinterpret_cast<const half8*>(&Wsh[FH_WD3T + j*16 + q*4]);
            #pragma unroll
            for (int e = 0; e < 8; ++e) {
                const float wf = (float)w[e];
                va = fmaf(h2a[q*8+e], wf, va);
                vb = fmaf(h2b[q*8+e], wf, vb);
            }
        }
        pra[j] = va; prb[j] = vb;
    }
    if (bv) {
        float* po = pred_out + (size_t)b * 36 + n * 6;
        *reinterpret_cast<float2*>(&po[0])  = make_float2(pra[0], pra[1]);
        *reinterpret_cast<float2*>(&po[2])  = make_float2(pra[2], pra[3]);
        *reinterpret_cast<float2*>(&po[4])  = make_float2(pra[4], pra[5]);
        *reinterpret_cast<float2*>(&po[18]) = make_float2(prb[0], prb[1]);
        *reinterpret_cast<float2*>(&po[20]) = make_float2(prb[2], prb[3]);
        *reinterpret_cast<float2*>(&po[22]) = make_float2(prb[4], prb[5]);
    }

    // ================= scorer =================
    float dfa[6], dfb[6];
    #pragma unroll
    for (int j = 0; j < 6; ++j) { dfa[j] = fabsf(fi0[j] - pra[j]); dfb[j] = fabsf(fi1[j] - prb[j]); }

    float s1a[32], s1b[32];
    #pragma unroll
    for (int o4 = 0; o4 < 8; ++o4) {
        const float4 v = *reinterpret_cast<const float4*>(&Wsh[FF_BS1 + o4*4]);
        s1a[o4*4+0] = v.x; s1a[o4*4+1] = v.y; s1a[o4*4+2] = v.z; s1a[o4*4+3] = v.w;
        s1b[o4*4+0] = v.x; s1b[o4*4+1] = v.y; s1b[o4*4+2] = v.z; s1b[o4*4+3] = v.w;
    }
    #pragma unroll
    for (int m = 0; m < 6; ++m) {
        const float aa = fi0[m], pa = pra[m], da = dfa[m];
        const float ab = fi1[m], pb = prb[m], db = dfb[m];
        #pragma unroll
        for (int q = 0; q < 4; ++q) {
            const half8 wa = *reinterpret_cast<const half8*>(&Wsh[FH_WS1 + m*16 + q*4]);
            const half8 wp = *reinterpret_cast<const half8*>(&Wsh[FH_WS1 + (6+m)*16 + q*4]);
            const half8 wd = *reinterpret_cast<const half8*>(&Wsh[FH_WS1 + (12+m)*16 + q*4]);
            #pragma unroll
            for (int e = 0; e < 8; ++e) {
                const int o = q*8 + e;
                const float x1 = (float)wa[e], x2 = (float)wp[e], x3 = (float)wd[e];
                s1a[o] = fmaf(aa, x1, fmaf(pa, x2, fmaf(da, x3, s1a[o])));
                s1b[o] = fmaf(ab, x1, fmaf(pb, x2, fmaf(db, x3, s1b[o])));
            }
        }
    }
    #pragma unroll
    for (int o = 0; o < 32; ++o) { s1a[o] = fmaxf(s1a[o], 0.0f); s1b[o] = fmaxf(s1b[o], 0.0f); }

    float s2a[16], s2b[16];
    #pragma unroll
    for (int o4 = 0; o4 < 4; ++o4) {
        const float4 v = *reinterpret_cast<const float4*>(&Wsh[FF_BS2 + o4*4]);
        s2a[o4*4+0] = v.x; s2a[o4*4+1] = v.y; s2a[o4*4+2] = v.z; s2a[o4*4+3] = v.w;
        s2b[o4*4+0] = v.x; s2b[o4*4+1] = v.y; s2b[o4*4+2] = v.z; s2b[o4*4+3] = v.w;
    }
    #pragma unroll
    for (int k = 0; k < 32; ++k) {
        const half8 w0 = *reinterpret_cast<const half8*>(&Wsh[FH_WS2 + k*8]);
        const half8 w1 = *reinterpret_cast<const half8*>(&Wsh[FH_WS2 + k*8 + 4]);
        const float xa = s1a[k], xb = s1b[k];
        #pragma unroll
        for (int e = 0; e < 8; ++e) {
            const float we0 = (float)w0[e], we1 = (float)w1[e];
            s2a[e]   = fmaf(xa, we0, s2a[e]);
            s2b[e]   = fmaf(xb, we0, s2b[e]);
            s2a[8+e] = fmaf(xa, we1, s2a[8+e]);
            s2b[8+e] = fmaf(xb, we1, s2b[8+e]);
        }
    }
    #pragma unroll
    for (int o = 0; o < 16; ++o) { s2a[o] = fmaxf(s2a[o], 0.0f); s2b[o] = fmaxf(s2b[o], 0.0f); }

    {
        const half8 w0 = *reinterpret_cast<const half8*>(&Wsh[FH_WS3]);
        const half8 w1 = *reinterpret_cast<const half8*>(&Wsh[FH_WS3 + 4]);
        float s3a = Wsh[FF_MISC], s3b = s3a;
        #pragma unroll
        for (int e = 0; e < 8; ++e) {
            const float we0 = (float)w0[e], we1 = (float)w1[e];
            s3a = fmaf(s2a[e], we0, s3a);   s3b = fmaf(s2b[e], we0, s3b);
            s3a = fmaf(s2a[8+e], we1, s3a); s3b = fmaf(s2b[8+e], we1, s3b);
        }
        if (act) {
            sc_s[sl_*6 + n]     = sigmoidf_(s3a);
            sc_s[sl_*6 + n + 3] = sigmoidf_(s3b);
        }
    }
    __syncthreads();

    if (bv && n == 0) {
        const float sum = sc_s[sl_*6+0] + sc_s[sl_*6+1] + sc_s[sl_*6+2]
                        + sc_s[sl_*6+3] + sc_s[sl_*6+4] + sc_s[sl_*6+5];
        scores[b] = sum * (1.0f / 6.0f);
    }
}

extern "C" void kernel_launch(void* const* d_in, const int* in_sizes, int n_in,
                              void* d_out, int out_size, void* d_ws, size_t ws_size,
                              hipStream_t stream) {
    const float* factors = (const float*)d_in[0];
    const float* Wn  = (const float*)d_in[1];
    const float* bn  = (const float*)d_in[2];
    const float* We1 = (const float*)d_in[3];
    const float* be1 = (const float*)d_in[4];
    const float* We2 = (const float*)d_in[5];
    const float* be2 = (const float*)d_in[6];
    const float* Wd1 = (const float*)d_in[7];
    const float* bd1 = (const float*)d_in[8];
    const float* Wd2 = (const float*)d_in[9];
    const float* bd2 = (const float*)d_in[10];
    const float* Wd3 = (const float*)d_in[11];
    const float* bd3 = (const float*)d_in[12];
    const float* Ws1 = (const float*)d_in[13];
    const float* bs1 = (const float*)d_in[14];
    const float* Ws2 = (const float*)d_in[15];
    const float* bs2 = (const float*)d_in[16];
    const float* Ws3 = (const float*)d_in[17];
    const float* bs3 = (const float*)d_in[18];

    const int B = in_sizes[0] / 36;

    float* adj_out  = (float*)d_out;                       // [B,6,6]
    float* pred_out = (float*)d_out + (size_t)B * 36;      // [B,6,6]
    float* scores   = (float*)d_out + (size_t)B * 72;      // [B]
    float* cat      = (float*)d_ws;                        // 1640 floats (f16-packed + f32 tail)

    hipLaunchKernelGGL(fold_kernel, dim3(1), dim3(512), 0, stream,
                       Wn, bn, We1, be1, We2, be2,
                       Wd1, bd1, Wd2, bd2, Wd3, bd3,
                       Ws1, bs1, Ws2, bs2, Ws3, bs3, cat);

    const int nblocks = (B + SPB - 1) / SPB;
    hipLaunchKernelGGL(fused5_kernel, dim3(nblocks), dim3(NT), 0, stream,
                       factors, cat, adj_out, pred_out, scores, B);
}

// Round 8
// 165.634 us; speedup vs baseline: 1.0515x; 1.0515x over previous
//
#include <hip/hip_runtime.h>
#include <math.h>

typedef _Float16 half8 __attribute__((ext_vector_type(8)));

#define NT  256
#define SPB 84          // samples/block, 3 threads/sample (rows n and n+3): 252 active

// ---- float-index offsets into Wsh (f32 view); weight tables are f16-packed ----
#define FH_REC   0      // 32 rows x 8 floats (16 f16/row): A[6],B[6],c0,w2,pad2
#define FH_WD1   256    // 6  x 16 (32 f16/row) [m][o]
#define FH_WD2   352    // 32 x 16 [k][o]
#define FH_WD3T  864    // 6  x 16 [j][k] (transposed)
#define FH_WS1   960    // 18 x 16 [m][o]
#define FH_WS2   1248   // 32 x 8  (16 f16/row) [k][o]
#define FH_WS3   1504   // 8  (16 f16)
#define FF_BD1   1512   // f32 region
#define FF_BD2   1544
#define FF_BD3   1576   // 6 + 2 pad
#define FF_BS1   1584
#define FF_BS2   1616
#define FF_MISC  1632   // [0]=bs3 [1]=be2
#define W_TOTF   1640   // 6560 bytes

#define ADJ_STRIDE 52

__device__ __forceinline__ float sigmoidf_(float x) {
    return 1.0f / (1.0f + __expf(-x));
}

// One block, 512 threads: fold edge weights, convert all tables to f16, pack into cat.
__global__ __launch_bounds__(512) void fold_kernel(
        const float* __restrict__ Wn,  const float* __restrict__ bn,
        const float* __restrict__ We1, const float* __restrict__ be1,
        const float* __restrict__ We2, const float* __restrict__ be2,
        const float* __restrict__ Wd1, const float* __restrict__ bd1,
        const float* __restrict__ Wd2, const float* __restrict__ bd2,
        const float* __restrict__ Wd3, const float* __restrict__ bd3,
        const float* __restrict__ Ws1, const float* __restrict__ bs1,
        const float* __restrict__ Ws2, const float* __restrict__ bs2,
        const float* __restrict__ Ws3, const float* __restrict__ bs3,
        float* __restrict__ cat) {
    _Float16* cath = (_Float16*)cat;
    const int t = threadIdx.x;
    // REC: 512 f16, one per thread
    {
        const int h = t >> 4, sl = t & 15;
        float val = 0.0f;
        if (sl < 6) {
            #pragma unroll
            for (int k = 0; k < 32; ++k) val = fmaf(Wn[sl*32+k], We1[k*32+h], val);
        } else if (sl < 12) {
            const int m = sl - 6;
            #pragma unroll
            for (int k = 0; k < 32; ++k) val = fmaf(Wn[m*32+k], We1[(32+k)*32+h], val);
        } else if (sl == 12) {
            #pragma unroll
            for (int k = 0; k < 32; ++k) val = fmaf(bn[k], We1[k*32+h] + We1[(32+k)*32+h], val);
            val += be1[h];
        } else if (sl == 13) {
            val = We2[h];
        }
        cath[h*16 + sl] = (_Float16)val;
    }
    // remaining f16 tables: half-index 512..3023
    for (int i = 512 + t; i < 3024; i += 512) {
        float v = 0.0f;
        if      (i < 704)  v = Wd1[i - 512];
        else if (i < 1728) v = Wd2[i - 704];
        else if (i < 1920) { const int q = i - 1728; v = Wd3[(q & 31)*6 + (q >> 5)]; }
        else if (i < 2496) v = Ws1[i - 1920];
        else if (i < 3008) v = Ws2[i - 2496];
        else               v = Ws3[i - 3008];
        cath[i] = (_Float16)v;
    }
    // f32 region: 128 floats at float-index 1512
    if (t < 128) {
        const int q = t;
        float v = 0.0f;
        if      (q < 32)  v = bd1[q];
        else if (q < 64)  v = bd2[q-32];
        else if (q < 70)  v = bd3[q-64];
        else if (q < 72)  v = 0.0f;
        else if (q < 104) v = bs1[q-72];
        else if (q < 120) v = bs2[q-104];
        else if (q == 120) v = bs3[0];
        else if (q == 121) v = be2[0];
        cat[1512 + q] = v;
    }
}

__global__ __launch_bounds__(NT, 1) void fused6_kernel(
        const float* __restrict__ factors, const float* __restrict__ cat,
        float* __restrict__ adj_out, float* __restrict__ pred_out,
        float* __restrict__ scores, int B) {
    __shared__ __align__(16) float Wsh[W_TOTF];
    __shared__ __align__(16) float adj_s[SPB * ADJ_STRIDE];
    __shared__ float sc_s[SPB * 6];

    const int t = threadIdx.x;
    // stage cat -> LDS (16B per thread per iter)
    #pragma unroll
    for (int i0 = 0; i0 < 2048; i0 += NT * 4) {
        const int i = i0 + t * 4;
        if (i < W_TOTF)
            *reinterpret_cast<float4*>(&Wsh[i]) = *reinterpret_cast<const float4*>(&cat[i]);
    }

    const int s = t / 3;
    const int n = t - s * 3;              // rows n and n+3
    const int b = blockIdx.x * SPB + s;
    const bool act = (t < SPB * 3);
    const int sl_ = (s < SPB) ? s : (SPB - 1);
    const bool bv = act && (b < B);

    float fall[36], fi0[6], fi1[6];
    #pragma unroll
    for (int q = 0; q < 36; ++q) fall[q] = 0.0f;
    #pragma unroll
    for (int m = 0; m < 6; ++m) { fi0[m] = 0.0f; fi1[m] = 0.0f; }
    if (bv) {
        const float* f = factors + (size_t)b * 36;
        #pragma unroll
        for (int q = 0; q < 9; ++q) {
            const float4 v = reinterpret_cast<const float4*>(f)[q];
            fall[q*4+0] = v.x; fall[q*4+1] = v.y; fall[q*4+2] = v.z; fall[q*4+3] = v.w;
        }
        // rule #20: runtime n must stay in the ADDRESS, not index a register array
        const float* fr0 = f + n * 6;        // row n
        const float* fr1 = fr0 + 18;         // row n+3
        #pragma unroll
        for (int q = 0; q < 3; ++q) {
            const float2 v0 = reinterpret_cast<const float2*>(fr0)[q];
            const float2 v1 = reinterpret_cast<const float2*>(fr1)[q];
            fi0[q*2+0] = v0.x; fi0[q*2+1] = v0.y;
            fi1[q*2+0] = v1.x; fi1[q*2+1] = v1.y;
        }
    }
    __syncthreads();

    // ================= edge phase (rows n, n+3; vj shared) =================
    float av0[6], av1[6];
    {
        float acc0[6] = {0.f,0.f,0.f,0.f,0.f,0.f};
        float acc1[6] = {0.f,0.f,0.f,0.f,0.f,0.f};
        #pragma unroll 4
        for (int h = 0; h < 32; ++h) {
            const half8 ha = *reinterpret_cast<const half8*>(&Wsh[FH_REC + h*8]);
            const half8 hb = *reinterpret_cast<const half8*>(&Wsh[FH_REC + h*8 + 4]);
            const float A0=(float)ha[0], A1=(float)ha[1], A2=(float)ha[2];
            const float A3=(float)ha[3], A4=(float)ha[4], A5=(float)ha[5];
            const float B0=(float)ha[6], B1=(float)ha[7], B2=(float)hb[0];
            const float B3=(float)hb[1], B4=(float)hb[2], B5=(float)hb[3];
            const float c0=(float)hb[4], w2=(float)hb[5];
            float uh0 = c0, uh1 = c0;
            uh0 = fmaf(fi0[0], A0, uh0); uh1 = fmaf(fi1[0], A0, uh1);
            uh0 = fmaf(fi0[1], A1, uh0); uh1 = fmaf(fi1[1], A1, uh1);
            uh0 = fmaf(fi0[2], A2, uh0); uh1 = fmaf(fi1[2], A2, uh1);
            uh0 = fmaf(fi0[3], A3, uh0); uh1 = fmaf(fi1[3], A3, uh1);
            uh0 = fmaf(fi0[4], A4, uh0); uh1 = fmaf(fi1[4], A4, uh1);
            uh0 = fmaf(fi0[5], A5, uh0); uh1 = fmaf(fi1[5], A5, uh1);
            #pragma unroll
            for (int j = 0; j < 6; ++j) {
                float vj = fall[j*6+0] * B0;
                vj = fmaf(fall[j*6+1], B1, vj);
                vj = fmaf(fall[j*6+2], B2, vj);
                vj = fmaf(fall[j*6+3], B3, vj);
                vj = fmaf(fall[j*6+4], B4, vj);
                vj = fmaf(fall[j*6+5], B5, vj);
                acc0[j] = fmaf(fmaxf(uh0 + vj, 0.0f), w2, acc0[j]);
                acc1[j] = fmaf(fmaxf(uh1 + vj, 0.0f), w2, acc1[j]);
            }
        }
        const float b2 = Wsh[FF_MISC + 1];
        #pragma unroll
        for (int j = 0; j < 6; ++j) {
            av0[j] = (j == n)     ? 0.0f : sigmoidf_(acc0[j] + b2);
            av1[j] = (j == n + 3) ? 0.0f : sigmoidf_(acc1[j] + b2);
        }
    }
    if (act) {
        float* as = &adj_s[sl_ * ADJ_STRIDE];
        *reinterpret_cast<float4*>(&as[n*8])       = make_float4(av0[0], av0[1], av0[2], av0[3]);
        *reinterpret_cast<float2*>(&as[n*8+4])     = make_float2(av0[4], av0[5]);
        *reinterpret_cast<float4*>(&as[(n+3)*8])   = make_float4(av1[0], av1[1], av1[2], av1[3]);
        *reinterpret_cast<float2*>(&as[(n+3)*8+4]) = make_float2(av1[4], av1[5]);
    }
    if (bv) {
        float* ao = adj_out + (size_t)b * 36 + n * 6;
        *reinterpret_cast<float2*>(&ao[0])  = make_float2(av0[0], av0[1]);
        *reinterpret_cast<float2*>(&ao[2])  = make_float2(av0[2], av0[3]);
        *reinterpret_cast<float2*>(&ao[4])  = make_float2(av0[4], av0[5]);
        *reinterpret_cast<float2*>(&ao[18]) = make_float2(av1[0], av1[1]);
        *reinterpret_cast<float2*>(&ao[20]) = make_float2(av1[2], av1[3]);
        *reinterpret_cast<float2*>(&ao[22]) = make_float2(av1[4], av1[5]);
    }
    __syncthreads();

    // ================= structured =================
    float st0[6], st1[6];
    {
        const float* as = &adj_s[sl_ * ADJ_STRIDE];
        #pragma unroll
        for (int i = 0; i < 6; ++i) {
            const float4 qa = *reinterpret_cast<const float4*>(&as[i*8]);
            const float2 qb = *reinterpret_cast<const float2*>(&as[i*8+4]);
            float v = fi0[0] * qa.x;
            v = fmaf(fi0[1], qa.y, v); v = fmaf(fi0[2], qa.z, v);
            v = fmaf(fi0[3], qa.w, v); v = fmaf(fi0[4], qb.x, v);
            v = fmaf(fi0[5], qb.y, v);
            st0[i] = v;
            float w = fi1[0] * qa.x;
            w = fmaf(fi1[1], qa.y, w); w = fmaf(fi1[2], qa.z, w);
            w = fmaf(fi1[3], qa.w, w); w = fmaf(fi1[4], qb.x, w);
            w = fmaf(fi1[5], qb.y, w);
            st1[i] = w;
        }
    }

    // ================= h1 = relu(st @ Wd1 + bd1) =================
    float h1a[32], h1b[32];
    #pragma unroll
    for (int o4 = 0; o4 < 8; ++o4) {
        const float4 v = *reinterpret_cast<const float4*>(&Wsh[FF_BD1 + o4*4]);
        h1a[o4*4+0] = v.x; h1a[o4*4+1] = v.y; h1a[o4*4+2] = v.z; h1a[o4*4+3] = v.w;
        h1b[o4*4+0] = v.x; h1b[o4*4+1] = v.y; h1b[o4*4+2] = v.z; h1b[o4*4+3] = v.w;
    }
    #pragma unroll
    for (int m = 0; m < 6; ++m) {
        const float xa = st0[m], xb = st1[m];
        #pragma unroll
        for (int q = 0; q < 4; ++q) {
            const half8 w = *reinterpret_cast<const half8*>(&Wsh[FH_WD1 + m*16 + q*4]);
            #pragma unroll
            for (int e = 0; e < 8; ++e) {
                const float wf = (float)w[e];
                h1a[q*8+e] = fmaf(xa, wf, h1a[q*8+e]);
                h1b[q*8+e] = fmaf(xb, wf, h1b[q*8+e]);
            }
        }
    }
    #pragma unroll
    for (int o = 0; o < 32; ++o) { h1a[o] = fmaxf(h1a[o], 0.0f); h1b[o] = fmaxf(h1b[o], 0.0f); }

    // ================= h2 = relu(h1 @ Wd2 + bd2), 2 passes of 16 outs =================
    float h2a[32], h2b[32];
    #pragma unroll
    for (int o4 = 0; o4 < 8; ++o4) {
        const float4 v = *reinterpret_cast<const float4*>(&Wsh[FF_BD2 + o4*4]);
        h2a[o4*4+0] = v.x; h2a[o4*4+1] = v.y; h2a[o4*4+2] = v.z; h2a[o4*4+3] = v.w;
        h2b[o4*4+0] = v.x; h2b[o4*4+1] = v.y; h2b[o4*4+2] = v.z; h2b[o4*4+3] = v.w;
    }
    #pragma unroll
    for (int p = 0; p < 2; ++p) {
        #pragma unroll
        for (int k = 0; k < 32; ++k) {
            const half8 w0 = *reinterpret_cast<const half8*>(&Wsh[FH_WD2 + k*16 + p*8]);
            const half8 w1 = *reinterpret_cast<const half8*>(&Wsh[FH_WD2 + k*16 + p*8 + 4]);
            const float xa = h1a[k], xb = h1b[k];
            #pragma unroll
            for (int e = 0; e < 8; ++e) {
                const float we0 = (float)w0[e], we1 = (float)w1[e];
                h2a[p*16+e]   = fmaf(xa, we0, h2a[p*16+e]);
                h2b[p*16+e]   = fmaf(xb, we0, h2b[p*16+e]);
                h2a[p*16+8+e] = fmaf(xa, we1, h2a[p*16+8+e]);
                h2b[p*16+8+e] = fmaf(xb, we1, h2b[p*16+8+e]);
            }
        }
    }
    #pragma unroll
    for (int o = 0; o < 32; ++o) { h2a[o] = fmaxf(h2a[o], 0.0f); h2b[o] = fmaxf(h2b[o], 0.0f); }

    // ================= pred = h2 @ Wd3 + bd3 (Wd3T [j][k]) =================
    float pra[6], prb[6];
    #pragma unroll
    for (int j = 0; j < 6; ++j) {
        float va = Wsh[FF_BD3 + j], vb = va;
        #pragma unroll
        for (int q = 0; q < 4; ++q) {
            const half8 w = *reinterpret_cast<const half8*>(&Wsh[FH_WD3T + j*16 + q*4]);
            #pragma unroll
            for (int e = 0; e < 8; ++e) {
                const float wf = (float)w[e];
                va = fmaf(h2a[q*8+e], wf, va);
                vb = fmaf(h2b[q*8+e], wf, vb);
            }
        }
        pra[j] = va; prb[j] = vb;
    }
    if (bv) {
        float* po = pred_out + (size_t)b * 36 + n * 6;
        *reinterpret_cast<float2*>(&po[0])  = make_float2(pra[0], pra[1]);
        *reinterpret_cast<float2*>(&po[2])  = make_float2(pra[2], pra[3]);
        *reinterpret_cast<float2*>(&po[4])  = make_float2(pra[4], pra[5]);
        *reinterpret_cast<float2*>(&po[18]) = make_float2(prb[0], prb[1]);
        *reinterpret_cast<float2*>(&po[20]) = make_float2(prb[2], prb[3]);
        *reinterpret_cast<float2*>(&po[22]) = make_float2(prb[4], prb[5]);
    }

    // ================= scorer =================
    float dfa[6], dfb[6];
    #pragma unroll
    for (int j = 0; j < 6; ++j) { dfa[j] = fabsf(fi0[j] - pra[j]); dfb[j] = fabsf(fi1[j] - prb[j]); }

    float s1a[32], s1b[32];
    #pragma unroll
    for (int o4 = 0; o4 < 8; ++o4) {
        const float4 v = *reinterpret_cast<const float4*>(&Wsh[FF_BS1 + o4*4]);
        s1a[o4*4+0] = v.x; s1a[o4*4+1] = v.y; s1a[o4*4+2] = v.z; s1a[o4*4+3] = v.w;
        s1b[o4*4+0] = v.x; s1b[o4*4+1] = v.y; s1b[o4*4+2] = v.z; s1b[o4*4+3] = v.w;
    }
    #pragma unroll
    for (int m = 0; m < 6; ++m) {
        const float aa = fi0[m], pa = pra[m], da = dfa[m];
        const float ab = fi1[m], pb = prb[m], db = dfb[m];
        #pragma unroll
        for (int q = 0; q < 4; ++q) {
            const half8 wa = *reinterpret_cast<const half8*>(&Wsh[FH_WS1 + m*16 + q*4]);
            const half8 wp = *reinterpret_cast<const half8*>(&Wsh[FH_WS1 + (6+m)*16 + q*4]);
            const half8 wd = *reinterpret_cast<const half8*>(&Wsh[FH_WS1 + (12+m)*16 + q*4]);
            #pragma unroll
            for (int e = 0; e < 8; ++e) {
                const int o = q*8 + e;
                const float x1 = (float)wa[e], x2 = (float)wp[e], x3 = (float)wd[e];
                s1a[o] = fmaf(aa, x1, fmaf(pa, x2, fmaf(da, x3, s1a[o])));
                s1b[o] = fmaf(ab, x1, fmaf(pb, x2, fmaf(db, x3, s1b[o])));
            }
        }
    }
    #pragma unroll
    for (int o = 0; o < 32; ++o) { s1a[o] = fmaxf(s1a[o], 0.0f); s1b[o] = fmaxf(s1b[o], 0.0f); }

    float s2a[16], s2b[16];
    #pragma unroll
    for (int o4 = 0; o4 < 4; ++o4) {
        const float4 v = *reinterpret_cast<const float4*>(&Wsh[FF_BS2 + o4*4]);
        s2a[o4*4+0] = v.x; s2a[o4*4+1] = v.y; s2a[o4*4+2] = v.z; s2a[o4*4+3] = v.w;
        s2b[o4*4+0] = v.x; s2b[o4*4+1] = v.y; s2b[o4*4+2] = v.z; s2b[o4*4+3] = v.w;
    }
    #pragma unroll
    for (int k = 0; k < 32; ++k) {
        const half8 w0 = *reinterpret_cast<const half8*>(&Wsh[FH_WS2 + k*8]);
        const half8 w1 = *reinterpret_cast<const half8*>(&Wsh[FH_WS2 + k*8 + 4]);
        const float xa = s1a[k], xb = s1b[k];
        #pragma unroll
        for (int e = 0; e < 8; ++e) {
            const float we0 = (float)w0[e], we1 = (float)w1[e];
            s2a[e]   = fmaf(xa, we0, s2a[e]);
            s2b[e]   = fmaf(xb, we0, s2b[e]);
            s2a[8+e] = fmaf(xa, we1, s2a[8+e]);
            s2b[8+e] = fmaf(xb, we1, s2b[8+e]);
        }
    }
    #pragma unroll
    for (int o = 0; o < 16; ++o) { s2a[o] = fmaxf(s2a[o], 0.0f); s2b[o] = fmaxf(s2b[o], 0.0f); }

    {
        const half8 w0 = *reinterpret_cast<const half8*>(&Wsh[FH_WS3]);
        const half8 w1 = *reinterpret_cast<const half8*>(&Wsh[FH_WS3 + 4]);
        float s3a = Wsh[FF_MISC], s3b = s3a;
        #pragma unroll
        for (int e = 0; e < 8; ++e) {
            const float we0 = (float)w0[e], we1 = (float)w1[e];
            s3a = fmaf(s2a[e], we0, s3a);   s3b = fmaf(s2b[e], we0, s3b);
            s3a = fmaf(s2a[8+e], we1, s3a); s3b = fmaf(s2b[8+e], we1, s3b);
        }
        if (act) {
            sc_s[sl_*6 + n]     = sigmoidf_(s3a);
            sc_s[sl_*6 + n + 3] = sigmoidf_(s3b);
        }
    }
    __syncthreads();

    if (bv && n == 0) {
        const float sum = sc_s[sl_*6+0] + sc_s[sl_*6+1] + sc_s[sl_*6+2]
                        + sc_s[sl_*6+3] + sc_s[sl_*6+4] + sc_s[sl_*6+5];
        scores[b] = sum * (1.0f / 6.0f);
    }
}

extern "C" void kernel_launch(void* const* d_in, const int* in_sizes, int n_in,
                              void* d_out, int out_size, void* d_ws, size_t ws_size,
                              hipStream_t stream) {
    const float* factors = (const float*)d_in[0];
    const float* Wn  = (const float*)d_in[1];
    const float* bn  = (const float*)d_in[2];
    const float* We1 = (const float*)d_in[3];
    const float* be1 = (const float*)d_in[4];
    const float* We2 = (const float*)d_in[5];
    const float* be2 = (const float*)d_in[6];
    const float* Wd1 = (const float*)d_in[7];
    const float* bd1 = (const float*)d_in[8];
    const float* Wd2 = (const float*)d_in[9];
    const float* bd2 = (const float*)d_in[10];
    const float* Wd3 = (const float*)d_in[11];
    const float* bd3 = (const float*)d_in[12];
    const float* Ws1 = (const float*)d_in[13];
    const float* bs1 = (const float*)d_in[14];
    const float* Ws2 = (const float*)d_in[15];
    const float* bs2 = (const float*)d_in[16];
    const float* Ws3 = (const float*)d_in[17];
    const float* bs3 = (const float*)d_in[18];

    const int B = in_sizes[0] / 36;

    float* adj_out  = (float*)d_out;                       // [B,6,6]
    float* pred_out = (float*)d_out + (size_t)B * 36;      // [B,6,6]
    float* scores   = (float*)d_out + (size_t)B * 72;      // [B]
    float* cat      = (float*)d_ws;                        // 1640 floats (f16-packed + f32 tail)

    hipLaunchKernelGGL(fold_kernel, dim3(1), dim3(512), 0, stream,
                       Wn, bn, We1, be1, We2, be2,
                       Wd1, bd1, Wd2, bd2, Wd3, bd3,
                       Ws1, bs1, Ws2, bs2, Ws3, bs3, cat);

    const int nblocks = (B + SPB - 1) / SPB;
    hipLaunchKernelGGL(fused6_kernel, dim3(nblocks), dim3(NT), 0, stream,
                       factors, cat, adj_out, pred_out, scores, B);
}

// Round 9
// 163.666 us; speedup vs baseline: 1.0642x; 1.0120x over previous
//
#include <hip/hip_runtime.h>
#include <math.h>

typedef _Float16 half8 __attribute__((ext_vector_type(8)));

#define NT  256
#define SPB 42          // samples/block, 6 threads (rows) per sample: 252 active

// ---- float-index offsets into Wsh (f32 view); weight tables are f16-packed ----
#define FH_REC   0      // 32 rows x 8 floats (16 f16/row): A[6],B[6],c0,w2,pad2
#define FH_WD1   256    // 6  x 16 floats (32 f16/row) [m][o]
#define FH_WD2   352    // 32 x 16 [k][o]
#define FH_WD3T  864    // 6  x 16 [j][k] (transposed)
#define FH_WS1   960    // 18 x 16 [m][o]
#define FH_WS2   1248   // 32 x 8  (16 f16/row) [k][o]
#define FH_WS3   1504   // 8  (16 f16)
#define FF_BD1   1512   // f32 region
#define FF_BD2   1544
#define FF_BD3   1576   // 6 + 2 pad
#define FF_BS1   1584
#define FF_BS2   1616
#define FF_MISC  1632   // [0]=bs3 [1]=be2
#define W_TOTF   1640   // 6560 bytes

#define ADJ_STRIDE 52

__device__ __forceinline__ float sigmoidf_(float x) {
    return 1.0f / (1.0f + __expf(-x));
}

// 8 blocks x 512 threads: fold edge weights + convert all tables to f16, pack into cat.
__global__ __launch_bounds__(512) void fold_kernel(
        const float* __restrict__ Wn,  const float* __restrict__ bn,
        const float* __restrict__ We1, const float* __restrict__ be1,
        const float* __restrict__ We2, const float* __restrict__ be2,
        const float* __restrict__ Wd1, const float* __restrict__ bd1,
        const float* __restrict__ Wd2, const float* __restrict__ bd2,
        const float* __restrict__ Wd3, const float* __restrict__ bd3,
        const float* __restrict__ Ws1, const float* __restrict__ bs1,
        const float* __restrict__ Ws2, const float* __restrict__ bs2,
        const float* __restrict__ Ws3, const float* __restrict__ bs3,
        float* __restrict__ cat) {
    _Float16* cath = (_Float16*)cat;
    const int t = threadIdx.x;
    const int bid = blockIdx.x;
    if (bid == 0) {
        // rec: 512 f16, one per thread (heavy fold)
        const int h = t >> 4, sl = t & 15;
        float val = 0.0f;
        if (sl < 6) {
            #pragma unroll
            for (int k = 0; k < 32; ++k) val = fmaf(Wn[sl*32+k], We1[k*32+h], val);
        } else if (sl < 12) {
            const int m = sl - 6;
            #pragma unroll
            for (int k = 0; k < 32; ++k) val = fmaf(Wn[m*32+k], We1[(32+k)*32+h], val);
        } else if (sl == 12) {
            #pragma unroll
            for (int k = 0; k < 32; ++k) val = fmaf(bn[k], We1[k*32+h] + We1[(32+k)*32+h], val);
            val += be1[h];
        } else if (sl == 13) {
            val = We2[h];
        }
        cath[h*16 + sl] = (_Float16)val;
    } else if (bid <= 5) {
        // f16 tables: half-index 512..3023, 512 per block
        const int i = 512 + (bid - 1) * 512 + t;
        if (i < 3024) {
            float v = 0.0f;
            if      (i < 704)  v = Wd1[i - 512];
            else if (i < 1728) v = Wd2[i - 704];
            else if (i < 1920) { const int q = i - 1728; v = Wd3[(q & 31)*6 + (q >> 5)]; }
            else if (i < 2496) v = Ws1[i - 1920];
            else if (i < 3008) v = Ws2[i - 2496];
            else               v = Ws3[i - 3008];
            cath[i] = (_Float16)v;
        }
    } else if (bid == 6) {
        // f32 tail: 128 floats at float-index 1512
        if (t < 128) {
            const int q = t;
            float v = 0.0f;
            if      (q < 32)  v = bd1[q];
            else if (q < 64)  v = bd2[q-32];
            else if (q < 70)  v = bd3[q-64];
            else if (q < 72)  v = 0.0f;
            else if (q < 104) v = bs1[q-72];
            else if (q < 120) v = bs2[q-104];
            else if (q == 120) v = bs3[0];
            else if (q == 121) v = be2[0];
            cat[1512 + q] = v;
        }
    }
}

__global__ __launch_bounds__(NT, 2) void fused7_kernel(
        const float* __restrict__ factors, const float* __restrict__ cat,
        float* __restrict__ adj_out, float* __restrict__ pred_out,
        float* __restrict__ scores, int B) {
    __shared__ __align__(16) float Wsh[W_TOTF];
    __shared__ __align__(16) float adj_s[SPB * ADJ_STRIDE];
    __shared__ float sc_s[SPB * 6];

    const int t = threadIdx.x;
    // stage cat -> LDS (float4, 2 iters)
    #pragma unroll
    for (int i0 = 0; i0 < 2048; i0 += NT * 4) {
        const int i = i0 + t * 4;
        if (i < W_TOTF)
            *reinterpret_cast<float4*>(&Wsh[i]) = *reinterpret_cast<const float4*>(&cat[i]);
    }

    const int s = t / 6;
    const int n = t - s * 6;
    const int b = blockIdx.x * SPB + s;
    const bool act = (t < SPB * 6);
    const bool bv = act && (b < B);
    const int sl_ = (s < SPB) ? s : (SPB - 1);

    float fall[36], fi[6];
    #pragma unroll
    for (int q = 0; q < 36; ++q) fall[q] = 0.0f;
    #pragma unroll
    for (int m = 0; m < 6; ++m) fi[m] = 0.0f;
    if (bv) {
        const float* f = factors + (size_t)b * 36;
        #pragma unroll
        for (int q = 0; q < 9; ++q) {
            const float4 v = reinterpret_cast<const float4*>(f)[q];
            fall[q*4+0] = v.x; fall[q*4+1] = v.y; fall[q*4+2] = v.z; fall[q*4+3] = v.w;
        }
        // rule #20: runtime n stays in the ADDRESS, not a register-array index
        const float* fr = f + n * 6;
        #pragma unroll
        for (int q = 0; q < 3; ++q) {
            const float2 v = reinterpret_cast<const float2*>(fr)[q];
            fi[q*2+0] = v.x; fi[q*2+1] = v.y;
        }
    }
    __syncthreads();

    // ================= edge phase =================
    float av[6];
    {
        float acc[6] = {0.f,0.f,0.f,0.f,0.f,0.f};
        #pragma unroll 4
        for (int h = 0; h < 32; ++h) {
            const half8 ha = *reinterpret_cast<const half8*>(&Wsh[FH_REC + h*8]);
            const half8 hb = *reinterpret_cast<const half8*>(&Wsh[FH_REC + h*8 + 4]);
            float uh = (float)hb[4];
            uh = fmaf(fi[0], (float)ha[0], uh);
            uh = fmaf(fi[1], (float)ha[1], uh);
            uh = fmaf(fi[2], (float)ha[2], uh);
            uh = fmaf(fi[3], (float)ha[3], uh);
            uh = fmaf(fi[4], (float)ha[4], uh);
            uh = fmaf(fi[5], (float)ha[5], uh);
            const float w2 = (float)hb[5];
            #pragma unroll
            for (int j = 0; j < 6; ++j) {
                float vj =      fall[j*6+0] * (float)ha[6];
                vj = fmaf(fall[j*6+1], (float)ha[7], vj);
                vj = fmaf(fall[j*6+2], (float)hb[0], vj);
                vj = fmaf(fall[j*6+3], (float)hb[1], vj);
                vj = fmaf(fall[j*6+4], (float)hb[2], vj);
                vj = fmaf(fall[j*6+5], (float)hb[3], vj);
                acc[j] = fmaf(fmaxf(uh + vj, 0.0f), w2, acc[j]);
            }
        }
        const float b2 = Wsh[FF_MISC + 1];
        #pragma unroll
        for (int j = 0; j < 6; ++j) av[j] = (j == n) ? 0.0f : sigmoidf_(acc[j] + b2);
    }
    if (act) {
        float* as = &adj_s[sl_ * ADJ_STRIDE + n * 8];
        *reinterpret_cast<float4*>(&as[0]) = make_float4(av[0], av[1], av[2], av[3]);
        *reinterpret_cast<float2*>(&as[4]) = make_float2(av[4], av[5]);
    }
    if (bv) {
        float* ao = adj_out + (size_t)b * 36 + n * 6;
        *reinterpret_cast<float2*>(&ao[0]) = make_float2(av[0], av[1]);
        *reinterpret_cast<float2*>(&ao[2]) = make_float2(av[2], av[3]);
        *reinterpret_cast<float2*>(&ao[4]) = make_float2(av[4], av[5]);
    }
    __syncthreads();

    // ================= structured =================
    float st[6];
    {
        const float* as = &adj_s[sl_ * ADJ_STRIDE];
        #pragma unroll
        for (int i = 0; i < 6; ++i) {
            const float4 qa = *reinterpret_cast<const float4*>(&as[i*8]);
            const float2 qb = *reinterpret_cast<const float2*>(&as[i*8+4]);
            float v = fi[0] * qa.x;
            v = fmaf(fi[1], qa.y, v); v = fmaf(fi[2], qa.z, v);
            v = fmaf(fi[3], qa.w, v); v = fmaf(fi[4], qb.x, v);
            v = fmaf(fi[5], qb.y, v);
            st[i] = v;
        }
    }

    // ================= h1 = relu(st @ Wd1 + bd1) =================
    float h1[32];
    #pragma unroll
    for (int o4 = 0; o4 < 8; ++o4) {
        const float4 v = *reinterpret_cast<const float4*>(&Wsh[FF_BD1 + o4*4]);
        h1[o4*4+0] = v.x; h1[o4*4+1] = v.y; h1[o4*4+2] = v.z; h1[o4*4+3] = v.w;
    }
    #pragma unroll
    for (int m = 0; m < 6; ++m) {
        const float x = st[m];
        #pragma unroll
        for (int q = 0; q < 4; ++q) {
            const half8 w = *reinterpret_cast<const half8*>(&Wsh[FH_WD1 + m*16 + q*4]);
            #pragma unroll
            for (int e = 0; e < 8; ++e) h1[q*8+e] = fmaf(x, (float)w[e], h1[q*8+e]);
        }
    }
    #pragma unroll
    for (int o = 0; o < 32; ++o) h1[o] = fmaxf(h1[o], 0.0f);

    // ================= h2 = relu(h1 @ Wd2 + bd2), 2 passes of 16 outs =================
    float h2[32];
    #pragma unroll
    for (int o4 = 0; o4 < 8; ++o4) {
        const float4 v = *reinterpret_cast<const float4*>(&Wsh[FF_BD2 + o4*4]);
        h2[o4*4+0] = v.x; h2[o4*4+1] = v.y; h2[o4*4+2] = v.z; h2[o4*4+3] = v.w;
    }
    #pragma unroll
    for (int p = 0; p < 2; ++p) {
        #pragma unroll
        for (int k = 0; k < 32; ++k) {
            const half8 w0 = *reinterpret_cast<const half8*>(&Wsh[FH_WD2 + k*16 + p*8]);
            const half8 w1 = *reinterpret_cast<const half8*>(&Wsh[FH_WD2 + k*16 + p*8 + 4]);
            const float x = h1[k];
            #pragma unroll
            for (int e = 0; e < 8; ++e) {
                h2[p*16+e]   = fmaf(x, (float)w0[e], h2[p*16+e]);
                h2[p*16+8+e] = fmaf(x, (float)w1[e], h2[p*16+8+e]);
            }
        }
    }
    #pragma unroll
    for (int o = 0; o < 32; ++o) h2[o] = fmaxf(h2[o], 0.0f);

    // ================= pred = h2 @ Wd3 + bd3 (Wd3T [j][k]) =================
    float pr[6];
    #pragma unroll
    for (int j = 0; j < 6; ++j) {
        float v = Wsh[FF_BD3 + j];
        #pragma unroll
        for (int q = 0; q < 4; ++q) {
            const half8 w = *reinterpret_cast<const half8*>(&Wsh[FH_WD3T + j*16 + q*4]);
            #pragma unroll
            for (int e = 0; e < 8; ++e) v = fmaf(h2[q*8+e], (float)w[e], v);
        }
        pr[j] = v;
    }
    if (bv) {
        float* po = pred_out + (size_t)b * 36 + n * 6;
        *reinterpret_cast<float2*>(&po[0]) = make_float2(pr[0], pr[1]);
        *reinterpret_cast<float2*>(&po[2]) = make_float2(pr[2], pr[3]);
        *reinterpret_cast<float2*>(&po[4]) = make_float2(pr[4], pr[5]);
    }

    // ================= scorer =================
    float df[6];
    #pragma unroll
    for (int j = 0; j < 6; ++j) df[j] = fabsf(fi[j] - pr[j]);

    float s1[32];
    #pragma unroll
    for (int o4 = 0; o4 < 8; ++o4) {
        const float4 v = *reinterpret_cast<const float4*>(&Wsh[FF_BS1 + o4*4]);
        s1[o4*4+0] = v.x; s1[o4*4+1] = v.y; s1[o4*4+2] = v.z; s1[o4*4+3] = v.w;
    }
    #pragma unroll
    for (int m = 0; m < 6; ++m) {
        const float a = fi[m], p = pr[m], d = df[m];
        #pragma unroll
        for (int q = 0; q < 4; ++q) {
            const half8 wa = *reinterpret_cast<const half8*>(&Wsh[FH_WS1 + m*16 + q*4]);
            const half8 wp = *reinterpret_cast<const half8*>(&Wsh[FH_WS1 + (6+m)*16 + q*4]);
            const half8 wd = *reinterpret_cast<const half8*>(&Wsh[FH_WS1 + (12+m)*16 + q*4]);
            #pragma unroll
            for (int e = 0; e < 8; ++e) {
                const int o = q*8 + e;
                s1[o] = fmaf(a, (float)wa[e], fmaf(p, (float)wp[e], fmaf(d, (float)wd[e], s1[o])));
            }
        }
    }
    #pragma unroll
    for (int o = 0; o < 32; ++o) s1[o] = fmaxf(s1[o], 0.0f);

    float s2[16];
    #pragma unroll
    for (int o4 = 0; o4 < 4; ++o4) {
        const float4 v = *reinterpret_cast<const float4*>(&Wsh[FF_BS2 + o4*4]);
        s2[o4*4+0] = v.x; s2[o4*4+1] = v.y; s2[o4*4+2] = v.z; s2[o4*4+3] = v.w;
    }
    #pragma unroll
    for (int k = 0; k < 32; ++k) {
        const half8 w0 = *reinterpret_cast<const half8*>(&Wsh[FH_WS2 + k*8]);
        const half8 w1 = *reinterpret_cast<const half8*>(&Wsh[FH_WS2 + k*8 + 4]);
        const float x = s1[k];
        #pragma unroll
        for (int e = 0; e < 8; ++e) {
            s2[e]   = fmaf(x, (float)w0[e], s2[e]);
            s2[8+e] = fmaf(x, (float)w1[e], s2[8+e]);
        }
    }
    #pragma unroll
    for (int o = 0; o < 16; ++o) s2[o] = fmaxf(s2[o], 0.0f);

    {
        const half8 w0 = *reinterpret_cast<const half8*>(&Wsh[FH_WS3]);
        const half8 w1 = *reinterpret_cast<const half8*>(&Wsh[FH_WS3 + 4]);
        float s3 = Wsh[FF_MISC];
        #pragma unroll
        for (int e = 0; e < 8; ++e) {
            s3 = fmaf(s2[e],   (float)w0[e], s3);
            s3 = fmaf(s2[8+e], (float)w1[e], s3);
        }
        if (act) sc_s[sl_ * 6 + n] = sigmoidf_(s3);
    }
    __syncthreads();

    if (bv && n == 0) {
        const float sum = sc_s[sl_*6+0] + sc_s[sl_*6+1] + sc_s[sl_*6+2]
                        + sc_s[sl_*6+3] + sc_s[sl_*6+4] + sc_s[sl_*6+5];
        scores[b] = sum * (1.0f / 6.0f);
    }
}

extern "C" void kernel_launch(void* const* d_in, const int* in_sizes, int n_in,
                              void* d_out, int out_size, void* d_ws, size_t ws_size,
                              hipStream_t stream) {
    const float* factors = (const float*)d_in[0];
    const float* Wn  = (const float*)d_in[1];
    const float* bn  = (const float*)d_in[2];
    const float* We1 = (const float*)d_in[3];
    const float* be1 = (const float*)d_in[4];
    const float* We2 = (const float*)d_in[5];
    const float* be2 = (const float*)d_in[6];
    const float* Wd1 = (const float*)d_in[7];
    const float* bd1 = (const float*)d_in[8];
    const float* Wd2 = (const float*)d_in[9];
    const float* bd2 = (const float*)d_in[10];
    const float* Wd3 = (const float*)d_in[11];
    const float* bd3 = (const float*)d_in[12];
    const float* Ws1 = (const float*)d_in[13];
    const float* bs1 = (const float*)d_in[14];
    const float* Ws2 = (const float*)d_in[15];
    const float* bs2 = (const float*)d_in[16];
    const float* Ws3 = (const float*)d_in[17];
    const float* bs3 = (const float*)d_in[18];

    const int B = in_sizes[0] / 36;

    float* adj_out  = (float*)d_out;                       // [B,6,6]
    float* pred_out = (float*)d_out + (size_t)B * 36;      // [B,6,6]
    float* scores   = (float*)d_out + (size_t)B * 72;      // [B]
    float* cat      = (float*)d_ws;                        // 1640 floats (f16-packed + f32 tail)

    hipLaunchKernelGGL(fold_kernel, dim3(8), dim3(512), 0, stream,
                       Wn, bn, We1, be1, We2, be2,
                       Wd1, bd1, Wd2, bd2, Wd3, bd3,
                       Ws1, bs1, Ws2, bs2, Ws3, bs3, cat);

    const int nblocks = (B + SPB - 1) / SPB;
    hipLaunchKernelGGL(fused7_kernel, dim3(nblocks), dim3(NT), 0, stream,
                       factors, cat, adj_out, pred_out, scores, B);
}